// Round 5
// baseline (270.790 us; speedup 1.0000x reference)
//
#include <hip/hip_runtime.h>
#include <cstddef>

typedef unsigned short u16;
typedef unsigned int u32;
typedef __attribute__((ext_vector_type(8))) __bf16 bf16x8;
typedef __attribute__((ext_vector_type(4))) float f32x4;

constexpr int kB = 8, kC = 256, kCI = 128, kN = 4096, kM = 1024;
constexpr float kEPS = 1e-5f;

__device__ __forceinline__ u16 f2bf(float f) {
    u32 u = __float_as_uint(f);
    u32 r = (u + 0x7fffu + ((u >> 16) & 1u)) >> 16;
    return (u16)r;
}

// ---------------------------------------------------------------------------
// prep: weights -> bf16; fold BN scale into Ww; bb = (bw-mean)*sc+beta
// ---------------------------------------------------------------------------
__global__ __launch_bounds__(256) void prep_kernel(const float* __restrict__ Wth,
                                                   const float* __restrict__ Wph,
                                                   const float* __restrict__ Wg,
                                                   const float* __restrict__ Ww,
                                                   const float* __restrict__ bw,
                                                   const float* __restrict__ gamma,
                                                   const float* __restrict__ beta,
                                                   const float* __restrict__ mean,
                                                   const float* __restrict__ var,
                                                   u16* __restrict__ Wthb,
                                                   u16* __restrict__ Wphb,
                                                   u16* __restrict__ Wgb,
                                                   u16* __restrict__ Wwsb,
                                                   float* __restrict__ bb) {
    int idx = blockIdx.x * 256 + threadIdx.x;
    if (idx < 32768) {
        Wthb[idx] = f2bf(Wth[idx]);
    } else if (idx < 65536) {
        int j = idx - 32768; Wphb[j] = f2bf(Wph[j]);
    } else if (idx < 98304) {
        int j = idx - 65536; Wgb[j] = f2bf(Wg[j]);
    } else {
        int j = idx - 98304;
        int co = j >> 7;
        float sc = gamma[co] * rsqrtf(var[co] + kEPS);
        Wwsb[j] = f2bf(Ww[j] * sc);
        if ((j & 127) == 0) bb[co] = (bw[co] - mean[co]) * sc + beta[co];
    }
}

// ---------------------------------------------------------------------------
// MFMA producer conv1x1 (+ optional fused 2x2 avg-pool on the input).
// x fp32: POOL=0: [b][256 c][Mn] ; POOL=1: [b][256 c][64][64] (Mn=1024 pooled)
// Wb bf16 [128 ci][256 c], bias fp32.
// CMAJOR=0: out bf16 [b][n][ci]  (theta, phi)
// CMAJOR=1: out bf16 [b][ci][n]  (g)
// block 256 thr / 4 waves; tile 64 px x 128 ci; K-chunks of 64.
// x staged transposed+swizzled: elem (n,c) at lds[n*64 + ((c>>3)^(n&7))*8 + (c&7)]
// ---------------------------------------------------------------------------
template <int CMAJOR, int POOL>
__global__ __launch_bounds__(256) void convp_kernel(const float* __restrict__ x,
                                                    const u16* __restrict__ Wb,
                                                    const float* __restrict__ bias,
                                                    u16* __restrict__ out, int Mn) {
    __shared__ __align__(16) u16 w_lds[128 * 72];   // [ci][c] stride 72
    __shared__ __align__(16) u16 x_lds[64 * 64];    // [n][c] swizzled, 128B rows
    int t = threadIdx.x, b = blockIdx.y, n0 = blockIdx.x * 64;
    int w = t >> 6, lane = t & 63, l15 = lane & 15, quad = lane >> 4;
    int xn = t & 63, cbb = (t >> 6) * 2;

    f32x4 acc[8];
#pragma unroll
    for (int i = 0; i < 8; i++) acc[i] = (f32x4){0.f, 0.f, 0.f, 0.f};

    for (int c0 = 0; c0 < kC; c0 += 64) {
        __syncthreads();
        // stage W chunk [128 ci][64 c]
#pragma unroll
        for (int i = 0; i < 4; i++) {
            int u = t + 256 * i;
            int ci = u >> 3, blk = u & 7;
            *(uint4*)&w_lds[ci * 72 + blk * 8] =
                *(const uint4*)&Wb[ci * kC + c0 + blk * 8];
        }
        // stage x chunk transposed: thread: n=xn, two 8-c blocks
#pragma unroll
        for (int cc = 0; cc < 2; cc++) {
            int cb = cbb + cc;
            float f[8];
            if (POOL) {
                int p = n0 + xn, ph_ = p >> 5, pw_ = p & 31;
#pragma unroll
                for (int j = 0; j < 8; j++) {
                    const float* src = x + ((size_t)(b * kC + c0 + cb * 8 + j) * 64
                                            + 2 * ph_) * 64 + 2 * pw_;
                    float2 a = *(const float2*)src;
                    float2 b2 = *(const float2*)(src + 64);
                    f[j] = 0.25f * (a.x + a.y + b2.x + b2.y);
                }
            } else {
#pragma unroll
                for (int j = 0; j < 8; j++)
                    f[j] = x[(size_t)(b * kC + c0 + cb * 8 + j) * Mn + n0 + xn];
            }
            uint4 pk;
            pk.x = (u32)f2bf(f[0]) | ((u32)f2bf(f[1]) << 16);
            pk.y = (u32)f2bf(f[2]) | ((u32)f2bf(f[3]) << 16);
            pk.z = (u32)f2bf(f[4]) | ((u32)f2bf(f[5]) << 16);
            pk.w = (u32)f2bf(f[6]) | ((u32)f2bf(f[7]) << 16);
            *(uint4*)&x_lds[xn * 64 + ((cb ^ (xn & 7)) * 8)] = pk;
        }
        __syncthreads();

#pragma unroll
        for (int ks = 0; ks < 2; ks++) {
            int px = w * 16 + l15;
            bf16x8 xf = *(const bf16x8*)&x_lds[px * 64 + (((ks * 4 + quad) ^ (px & 7)) * 8)];
#pragma unroll
            for (int ct = 0; ct < 8; ct++) {
                bf16x8 wf = *(const bf16x8*)&w_lds[(ct * 16 + l15) * 72 + ks * 32 + quad * 8];
                if (CMAJOR)
                    acc[ct] = __builtin_amdgcn_mfma_f32_16x16x32_bf16(xf, wf, acc[ct], 0, 0, 0);
                else
                    acc[ct] = __builtin_amdgcn_mfma_f32_16x16x32_bf16(wf, xf, acc[ct], 0, 0, 0);
            }
        }
    }

    if (CMAJOR == 0) {
        int px = n0 + w * 16 + l15;
#pragma unroll
        for (int ct = 0; ct < 8; ct++) {
            int ci0 = ct * 16 + quad * 4;
            uint2 pk;
            pk.x = (u32)f2bf(acc[ct][0] + bias[ci0 + 0]) |
                   ((u32)f2bf(acc[ct][1] + bias[ci0 + 1]) << 16);
            pk.y = (u32)f2bf(acc[ct][2] + bias[ci0 + 2]) |
                   ((u32)f2bf(acc[ct][3] + bias[ci0 + 3]) << 16);
            *(uint2*)&out[(size_t)(b * Mn + px) * kCI + ci0] = pk;
        }
    } else {
        int px = n0 + w * 16 + quad * 4;
#pragma unroll
        for (int ct = 0; ct < 8; ct++) {
            int ci = ct * 16 + l15;
            float bs = bias[ci];
            uint2 pk;
            pk.x = (u32)f2bf(acc[ct][0] + bs) | ((u32)f2bf(acc[ct][1] + bs) << 16);
            pk.y = (u32)f2bf(acc[ct][2] + bs) | ((u32)f2bf(acc[ct][3] + bs) << 16);
            *(uint2*)&out[(size_t)(b * kCI + ci) * Mn + px] = pk;
        }
    }
}

// ---------------------------------------------------------------------------
// Transposed flash attention, bf16 MFMA.
// theta [B][N][CI], phi [B][M][CI], g [B][CI][M] (all bf16); y bf16 [B][N][CI].
// S' = phi . theta^T (C-layout col = n), O' = G^T . P' (C-layout col = n).
// block = 128 thr (2 waves); wave owns 32 n (2 nt tiles); m-chunks of 64.
// LDS frag-order layouts: every wave frag read = contiguous 1024B (no conflicts).
// ---------------------------------------------------------------------------
__global__ __launch_bounds__(128) void attn_kernel(const u16* __restrict__ theta,
                                                   const u16* __restrict__ phi,
                                                   const u16* __restrict__ g,
                                                   u16* __restrict__ y) {
    __shared__ __align__(16) u16 ph_lds[8192];   // [ks:4][m:64][q:4][8]
    __shared__ __align__(16) u16 g_lds[8192];    // [ks2:2][ci:128][q:4][8]
    __shared__ __align__(16) u16 p_lds[4096];    // [wave:2][frag:4][lane:64][8]

    int t = threadIdx.x, b = blockIdx.y, n0 = blockIdx.x * 64;
    int w = t >> 6, lane = t & 63, l15 = lane & 15, quad = lane >> 4;

    // theta B-frags held in registers for the whole kernel
    bf16x8 thf[2][4];
    const u16* thB = theta + ((size_t)(b * kN) + n0 + w * 32) * kCI;
#pragma unroll
    for (int nt = 0; nt < 2; nt++)
#pragma unroll
        for (int ks = 0; ks < 4; ks++)
            thf[nt][ks] = *(const bf16x8*)&thB[(size_t)(nt * 16 + l15) * kCI + ks * 32 + quad * 8];

    f32x4 oacc[8][2];
#pragma unroll
    for (int ct = 0; ct < 8; ct++) {
        oacc[ct][0] = (f32x4){0.f, 0.f, 0.f, 0.f};
        oacc[ct][1] = (f32x4){0.f, 0.f, 0.f, 0.f};
    }
    float m_[2] = {-1e30f, -1e30f}, l_[2] = {0.f, 0.f};

    const u16* phB = phi + (size_t)b * kM * kCI;
    const u16* gB  = g   + (size_t)b * kCI * kM;
    u16* pw = p_lds + w * 2048;

    for (int c0 = 0; c0 < kM; c0 += 64) {
        __syncthreads();
        // stage phi chunk -> frag order [ks][m][q][8]
#pragma unroll
        for (int it = 0; it < 8; it++) {
            int u = t + 128 * it;
            int row = u >> 4, cb = u & 15;
            *(uint4*)&ph_lds[(cb >> 2) * 2048 + row * 32 + (cb & 3) * 8] =
                *(const uint4*)&phB[(size_t)(c0 + row) * kCI + cb * 8];
        }
        // stage g chunk -> frag order [ks2][ci][q][8]
#pragma unroll
        for (int it = 0; it < 8; it++) {
            int u = t + 128 * it;
            int ci = u >> 3, mb = u & 7;
            *(uint4*)&g_lds[(mb >> 2) * 4096 + ci * 32 + (mb & 3) * 8] =
                *(const uint4*)&gB[(size_t)ci * kM + c0 + mb * 8];
        }
        __syncthreads();

        // S' = phi(64m x 128k) . theta^T -> tiles [mt][nt], C-col = n
        f32x4 sacc[4][2];
#pragma unroll
        for (int mt = 0; mt < 4; mt++) {
            sacc[mt][0] = (f32x4){0.f, 0.f, 0.f, 0.f};
            sacc[mt][1] = (f32x4){0.f, 0.f, 0.f, 0.f};
        }
#pragma unroll
        for (int ks = 0; ks < 4; ks++)
#pragma unroll
            for (int mt = 0; mt < 4; mt++) {
                bf16x8 a = *(const bf16x8*)&ph_lds[ks * 2048 + (mt * 16 + l15) * 32 + quad * 8];
                sacc[mt][0] = __builtin_amdgcn_mfma_f32_16x16x32_bf16(a, thf[0][ks], sacc[mt][0], 0, 0, 0);
                sacc[mt][1] = __builtin_amdgcn_mfma_f32_16x16x32_bf16(a, thf[1][ks], sacc[mt][1], 0, 0, 0);
            }

        // online softmax over m (lane-uniform per n); pack P' -> per-wave frag LDS
#pragma unroll
        for (int nt = 0; nt < 2; nt++) {
            float mc = -1e30f;
#pragma unroll
            for (int mt = 0; mt < 4; mt++)
#pragma unroll
                for (int r = 0; r < 4; r++) mc = fmaxf(mc, sacc[mt][nt][r]);
            mc = fmaxf(mc, __shfl_xor(mc, 16, 64));
            mc = fmaxf(mc, __shfl_xor(mc, 32, 64));
            float mp = m_[nt];
            float mn = fmaxf(mp, mc);
            int resc = __any(mn != mp);
            float alpha = __expf(mp - mn);
            m_[nt] = mn;
            float rs = 0.f;
#pragma unroll
            for (int mt = 0; mt < 4; mt++)
#pragma unroll
                for (int r = 0; r < 4; r++) {
                    float p = __expf(sacc[mt][nt][r] - mn);
                    sacc[mt][nt][r] = p;
                    rs += p;
                }
            rs += __shfl_xor(rs, 16, 64);
            rs += __shfl_xor(rs, 32, 64);
            l_[nt] = l_[nt] * alpha + rs;
            if (resc) {
#pragma unroll
                for (int ct = 0; ct < 8; ct++)
#pragma unroll
                    for (int r = 0; r < 4; r++) oacc[ct][nt][r] *= alpha;
            }
            // pack pairs (RN-ish) and scatter to B-frag slots
#pragma unroll
            for (int mt = 0; mt < 4; mt++)
#pragma unroll
                for (int h = 0; h < 2; h++) {
                    u32 ue = __float_as_uint(sacc[mt][nt][2 * h]) + 0x8000u;
                    u32 uo = __float_as_uint(sacc[mt][nt][2 * h + 1]) + 0x8000u;
                    u32 d = (ue >> 16) | (uo & 0xffff0000u);
                    int m = mt * 16 + quad * 4 + 2 * h;
                    int off = ((m >> 5) * 2 + nt) * 512 + (((m >> 3) & 3) * 16 + l15) * 8 + (m & 7);
                    *(u32*)&pw[off] = d;
                }
        }

        // O' += G^T(128ci x 64m) . P'(64m x n)
#pragma unroll
        for (int ks2 = 0; ks2 < 2; ks2++) {
            bf16x8 b0 = *(const bf16x8*)&pw[(ks2 * 2 + 0) * 512 + (quad * 16 + l15) * 8];
            bf16x8 b1 = *(const bf16x8*)&pw[(ks2 * 2 + 1) * 512 + (quad * 16 + l15) * 8];
#pragma unroll
            for (int ct = 0; ct < 8; ct++) {
                bf16x8 a = *(const bf16x8*)&g_lds[ks2 * 4096 + (ct * 16 + l15) * 32 + quad * 8];
                oacc[ct][0] = __builtin_amdgcn_mfma_f32_16x16x32_bf16(a, b0, oacc[ct][0], 0, 0, 0);
                oacc[ct][1] = __builtin_amdgcn_mfma_f32_16x16x32_bf16(a, b1, oacc[ct][1], 0, 0, 0);
            }
        }
    }

    // epilogue: y[n][ci] = O'/l ; n = col = l15 (lane-uniform inv)
#pragma unroll
    for (int nt = 0; nt < 2; nt++) {
        float inv = 1.0f / l_[nt];
        int n = n0 + w * 32 + nt * 16 + l15;
        u16* yr = y + ((size_t)(b * kN) + n) * kCI + quad * 4;
#pragma unroll
        for (int ct = 0; ct < 8; ct++) {
            uint2 pk;
            pk.x = (u32)f2bf(oacc[ct][nt][0] * inv) | ((u32)f2bf(oacc[ct][nt][1] * inv) << 16);
            pk.y = (u32)f2bf(oacc[ct][nt][2] * inv) | ((u32)f2bf(oacc[ct][nt][3] * inv) << 16);
            *(uint2*)&yr[ct * 16] = pk;
        }
    }
}

// ---------------------------------------------------------------------------
// MFMA final conv: out[b][co][n] = Wws(bf16 [256][128]) . y(bf16 [b][n][128])
//                  + bb[co] + v[b][co][n]   (fp32 out)
// ---------------------------------------------------------------------------
__global__ __launch_bounds__(256) void final_kernel(const u16* __restrict__ y,
                                                    const u16* __restrict__ Wws,
                                                    const float* __restrict__ bb,
                                                    const float* __restrict__ v,
                                                    float* __restrict__ out) {
    __shared__ __align__(16) u16 y_lds[64 * 136];
    int t = threadIdx.x, b = blockIdx.y, n0 = blockIdx.x * 64;
    int w = t >> 6, lane = t & 63, l15 = lane & 15, quad = lane >> 4;

#pragma unroll
    for (int i = 0; i < 4; i++) {
        int u = t + 256 * i;
        int row = u >> 4, blk = u & 15;
        *(uint4*)&y_lds[row * 136 + blk * 8] =
            *(const uint4*)&y[(size_t)(b * kN + n0 + row) * kCI + blk * 8];
    }
    __syncthreads();

    bf16x8 af[4];
#pragma unroll
    for (int ks = 0; ks < 4; ks++)
        af[ks] = *(const bf16x8*)&y_lds[(w * 16 + l15) * 136 + ks * 32 + quad * 8];

#pragma unroll
    for (int ct = 0; ct < 16; ct++) {
        f32x4 a = (f32x4){0.f, 0.f, 0.f, 0.f};
#pragma unroll
        for (int ks = 0; ks < 4; ks++) {
            bf16x8 bf = *(const bf16x8*)&Wws[(ct * 16 + l15) * kCI + ks * 32 + quad * 8];
            a = __builtin_amdgcn_mfma_f32_16x16x32_bf16(af[ks], bf, a, 0, 0, 0);
        }
        int co = ct * 16 + l15;
        float bbv = bb[co];
        size_t base = (size_t)(b * kC + co) * kN + n0 + w * 16 + quad * 4;
        float4 vv = *(const float4*)&v[base];
        float4 ov;
        ov.x = a[0] + bbv + vv.x;
        ov.y = a[1] + bbv + vv.y;
        ov.z = a[2] + bbv + vv.z;
        ov.w = a[3] + bbv + vv.w;
        *(float4*)&out[base] = ov;
    }
}

// ---------------------------------------------------------------------------
extern "C" void kernel_launch(void* const* d_in, const int* in_sizes, int n_in,
                              void* d_out, int out_size, void* d_ws, size_t ws_size,
                              hipStream_t stream) {
    (void)in_sizes; (void)n_in; (void)out_size; (void)ws_size;
    const float* q     = (const float*)d_in[0];
    const float* k     = (const float*)d_in[1];
    const float* v     = (const float*)d_in[2];
    const float* Wg    = (const float*)d_in[3];
    const float* bg    = (const float*)d_in[4];
    const float* Wth   = (const float*)d_in[5];
    const float* bth   = (const float*)d_in[6];
    const float* Wph   = (const float*)d_in[7];
    const float* bph   = (const float*)d_in[8];
    const float* Ww    = (const float*)d_in[9];
    const float* bw    = (const float*)d_in[10];
    const float* gamma = (const float*)d_in[11];
    const float* beta  = (const float*)d_in[12];
    const float* mean  = (const float*)d_in[13];
    const float* var   = (const float*)d_in[14];
    float* out = (float*)d_out;

    u16* wsu = (u16*)d_ws;
    u16*   theta = wsu;                       // 4M u16
    u16*   phi   = theta + 4194304;           // 1M u16
    u16*   gbuf  = phi + 1048576;             // 1M u16
    u16*   ybuf  = gbuf + 1048576;            // 4M u16
    u16*   Wthb  = ybuf + 4194304;
    u16*   Wphb  = Wthb + 32768;
    u16*   Wgb   = Wphb + 32768;
    u16*   Wwsb  = Wgb + 32768;
    float* bbuf  = (float*)(Wwsb + 32768);

    prep_kernel<<<dim3(512), 256, 0, stream>>>(Wth, Wph, Wg, Ww, bw, gamma, beta,
                                               mean, var, Wthb, Wphb, Wgb, Wwsb, bbuf);
    convp_kernel<0, 0><<<dim3(64, 8), 256, 0, stream>>>(k, Wthb, bth, theta, kN);
    convp_kernel<0, 1><<<dim3(16, 8), 256, 0, stream>>>(q, Wphb, bph, phi, kM);
    convp_kernel<1, 1><<<dim3(16, 8), 256, 0, stream>>>(v, Wgb, bg, gbuf, kM);
    attn_kernel<<<dim3(64, 8), 128, 0, stream>>>(theta, phi, gbuf, ybuf);
    final_kernel<<<dim3(64, 8), 256, 0, stream>>>(ybuf, Wwsb, bbuf, v, out);
}

// Round 6
// 254.163 us; speedup vs baseline: 1.0654x; 1.0654x over previous
//
#include <hip/hip_runtime.h>
#include <cstddef>

typedef unsigned short u16;
typedef unsigned int u32;
typedef __attribute__((ext_vector_type(8))) __bf16 bf16x8;
typedef __attribute__((ext_vector_type(4))) float f32x4;

constexpr int kB = 8, kC = 256, kCI = 128, kN = 4096, kM = 1024;
constexpr float kEPS = 1e-5f;

__device__ __forceinline__ u16 f2bf(float f) {
    u32 u = __float_as_uint(f);
    u32 r = (u + 0x7fffu + ((u >> 16) & 1u)) >> 16;
    return (u16)r;
}

// ---------------------------------------------------------------------------
// prep: weights -> bf16; fold BN scale into Ww; bb = (bw-mean)*sc+beta
// ---------------------------------------------------------------------------
__global__ __launch_bounds__(256) void prep_kernel(const float* __restrict__ Wth,
                                                   const float* __restrict__ Wph,
                                                   const float* __restrict__ Wg,
                                                   const float* __restrict__ Ww,
                                                   const float* __restrict__ bw,
                                                   const float* __restrict__ gamma,
                                                   const float* __restrict__ beta,
                                                   const float* __restrict__ mean,
                                                   const float* __restrict__ var,
                                                   u16* __restrict__ Wthb,
                                                   u16* __restrict__ Wphb,
                                                   u16* __restrict__ Wgb,
                                                   u16* __restrict__ Wwsb,
                                                   float* __restrict__ bb) {
    int idx = blockIdx.x * 256 + threadIdx.x;
    if (idx < 32768) {
        Wthb[idx] = f2bf(Wth[idx]);
    } else if (idx < 65536) {
        int j = idx - 32768; Wphb[j] = f2bf(Wph[j]);
    } else if (idx < 98304) {
        int j = idx - 65536; Wgb[j] = f2bf(Wg[j]);
    } else {
        int j = idx - 98304;
        int co = j >> 7;
        float sc = gamma[co] * rsqrtf(var[co] + kEPS);
        Wwsb[j] = f2bf(Ww[j] * sc);
        if ((j & 127) == 0) bb[co] = (bw[co] - mean[co]) * sc + beta[co];
    }
}

// ---------------------------------------------------------------------------
// MFMA producer conv1x1 body (optionally fused 2x2 avg-pool on input).
// x fp32: POOL=0: [b][256 c][Mn] ; POOL=1: [b][256 c][64][64] (Mn=1024 pooled)
// Wb bf16 [128 ci][256 c], bias fp32.
// cmajor=0: out bf16 [b][n][ci]  (theta, phi);  cmajor=1: out bf16 [b][ci][n] (g)
// block 256 thr / 4 waves; tile 64 px x 128 ci; K-chunks of 64.
// x_lds swizzle: (n,c) at [n*64 + ((c>>3)^(n&7))*8 + (c&7)]  (conflict-free)
// ---------------------------------------------------------------------------
template <int POOL>
__device__ __forceinline__ void conv_body(const float* __restrict__ x,
                                          const u16* __restrict__ Wb,
                                          const float* __restrict__ bias,
                                          u16* __restrict__ out, int Mn,
                                          int cmajor, int b, int n0) {
    __shared__ __align__(16) u16 w_lds[128 * 72];   // [ci][c] stride 72 (16B-offset rows)
    __shared__ __align__(16) u16 x_lds[64 * 64];    // [n][c] swizzled
    int t = threadIdx.x;
    int w = t >> 6, lane = t & 63, l15 = lane & 15, quad = lane >> 4;
    int xn = t & 63, cbb = (t >> 6) * 2;

    f32x4 acc[8];
#pragma unroll
    for (int i = 0; i < 8; i++) acc[i] = (f32x4){0.f, 0.f, 0.f, 0.f};

    for (int c0 = 0; c0 < kC; c0 += 64) {
        __syncthreads();
#pragma unroll
        for (int i = 0; i < 4; i++) {
            int u = t + 256 * i;
            int ci = u >> 3, blk = u & 7;
            *(uint4*)&w_lds[ci * 72 + blk * 8] =
                *(const uint4*)&Wb[ci * kC + c0 + blk * 8];
        }
#pragma unroll
        for (int cc = 0; cc < 2; cc++) {
            int cb = cbb + cc;
            float f[8];
            if (POOL) {
                int p = n0 + xn, ph_ = p >> 5, pw_ = p & 31;
#pragma unroll
                for (int j = 0; j < 8; j++) {
                    const float* src = x + ((size_t)(b * kC + c0 + cb * 8 + j) * 64
                                            + 2 * ph_) * 64 + 2 * pw_;
                    float2 a = *(const float2*)src;
                    float2 b2 = *(const float2*)(src + 64);
                    f[j] = 0.25f * (a.x + a.y + b2.x + b2.y);
                }
            } else {
#pragma unroll
                for (int j = 0; j < 8; j++)
                    f[j] = x[(size_t)(b * kC + c0 + cb * 8 + j) * Mn + n0 + xn];
            }
            uint4 pk;
            pk.x = (u32)f2bf(f[0]) | ((u32)f2bf(f[1]) << 16);
            pk.y = (u32)f2bf(f[2]) | ((u32)f2bf(f[3]) << 16);
            pk.z = (u32)f2bf(f[4]) | ((u32)f2bf(f[5]) << 16);
            pk.w = (u32)f2bf(f[6]) | ((u32)f2bf(f[7]) << 16);
            *(uint4*)&x_lds[xn * 64 + ((cb ^ (xn & 7)) * 8)] = pk;
        }
        __syncthreads();

#pragma unroll
        for (int ks = 0; ks < 2; ks++) {
            int px = w * 16 + l15;
            bf16x8 xf = *(const bf16x8*)&x_lds[px * 64 + (((ks * 4 + quad) ^ (px & 7)) * 8)];
#pragma unroll
            for (int ct = 0; ct < 8; ct++) {
                bf16x8 wf = *(const bf16x8*)&w_lds[(ct * 16 + l15) * 72 + ks * 32 + quad * 8];
                if (cmajor)
                    acc[ct] = __builtin_amdgcn_mfma_f32_16x16x32_bf16(xf, wf, acc[ct], 0, 0, 0);
                else
                    acc[ct] = __builtin_amdgcn_mfma_f32_16x16x32_bf16(wf, xf, acc[ct], 0, 0, 0);
            }
        }
    }

    if (cmajor == 0) {
        int px = n0 + w * 16 + l15;
#pragma unroll
        for (int ct = 0; ct < 8; ct++) {
            int ci0 = ct * 16 + quad * 4;
            uint2 pk;
            pk.x = (u32)f2bf(acc[ct][0] + bias[ci0 + 0]) |
                   ((u32)f2bf(acc[ct][1] + bias[ci0 + 1]) << 16);
            pk.y = (u32)f2bf(acc[ct][2] + bias[ci0 + 2]) |
                   ((u32)f2bf(acc[ct][3] + bias[ci0 + 3]) << 16);
            *(uint2*)&out[(size_t)(b * Mn + px) * kCI + ci0] = pk;
        }
    } else {
        int px = n0 + w * 16 + quad * 4;
#pragma unroll
        for (int ct = 0; ct < 8; ct++) {
            int ci = ct * 16 + l15;
            float bs = bias[ci];
            uint2 pk;
            pk.x = (u32)f2bf(acc[ct][0] + bs) | ((u32)f2bf(acc[ct][1] + bs) << 16);
            pk.y = (u32)f2bf(acc[ct][2] + bs) | ((u32)f2bf(acc[ct][3] + bs) << 16);
            *(uint2*)&out[(size_t)(b * kCI + ci) * Mn + px] = pk;
        }
    }
}

// theta conv: no pool, n-major out
__global__ __launch_bounds__(256) void convth_kernel(const float* __restrict__ x,
                                                     const u16* __restrict__ Wb,
                                                     const float* __restrict__ bias,
                                                     u16* __restrict__ out) {
    conv_body<0>(x, Wb, bias, out, kN, 0, blockIdx.y, blockIdx.x * 64);
}

// fused phi (z=0, n-major) + g (z=1, ci-major) convs with pooled input
__global__ __launch_bounds__(256) void convpg_kernel(const float* __restrict__ q,
                                                     const float* __restrict__ v,
                                                     const u16* __restrict__ Wph,
                                                     const u16* __restrict__ Wg,
                                                     const float* __restrict__ bph,
                                                     const float* __restrict__ bg,
                                                     u16* __restrict__ phi,
                                                     u16* __restrict__ g) {
    int z = blockIdx.z;
    conv_body<1>(z ? v : q, z ? Wg : Wph, z ? bg : bph, z ? g : phi,
                 kM, z, blockIdx.y, blockIdx.x * 64);
}

// ---------------------------------------------------------------------------
// Transposed flash attention, bf16 MFMA, swizzled conflict-free LDS.
// theta [B][N][CI], phi [B][M][CI], g [B][CI][M] (bf16); y bf16 [B][N][CI].
// S' = phi . theta^T (C-col = n), O' = G^T . P' (C-col = n).
// 256 thr / 4 waves; wave owns 16 n; m-chunks of 64.
// All frag tiles: [frag][row][kblk^((row>>1)&3)][8] -> octets cover 8 distinct
// 16B positions mod 128B (conflict-free b128); staging/scatter <=2-way.
// ---------------------------------------------------------------------------
__global__ __launch_bounds__(256) void attn_kernel(const u16* __restrict__ theta,
                                                   const u16* __restrict__ phi,
                                                   const u16* __restrict__ g,
                                                   u16* __restrict__ y) {
    __shared__ __align__(16) u16 ph_lds[8192];   // [ks:4][m:64][kblk:4][8]  16KB
    __shared__ __align__(16) u16 g_lds[8192];    // [ks2:2][ci:128][kblk:4][8] 16KB
    __shared__ __align__(16) u16 p_lds[4096];    // [wave:4][frag:2][col:16][k:32] 8KB

    int t = threadIdx.x, b = blockIdx.y, n0 = blockIdx.x * 64;
    int w = t >> 6, lane = t & 63, l15 = lane & 15, quad = lane >> 4;
    int sw = (l15 >> 1) & 3;                     // row-swizzle key for row=l15 patterns

    // theta B-frags in registers for the whole kernel (16 n per wave)
    bf16x8 thf[4];
    const u16* thB = theta + ((size_t)(b * kN) + n0 + w * 16 + l15) * kCI;
#pragma unroll
    for (int ks = 0; ks < 4; ks++)
        thf[ks] = *(const bf16x8*)&thB[ks * 32 + quad * 8];

    f32x4 oacc[8];
#pragma unroll
    for (int ct = 0; ct < 8; ct++) oacc[ct] = (f32x4){0.f, 0.f, 0.f, 0.f};
    float m_ = -1e30f, l_ = 0.f;

    const u16* phB = phi + (size_t)b * kM * kCI;
    const u16* gB  = g   + (size_t)b * kCI * kM;
    u16* pw = p_lds + w * 1024;

    for (int c0 = 0; c0 < kM; c0 += 64) {
        __syncthreads();
        // stage phi chunk [64 m][128 ci] -> [ks][m][kblk^((m>>1)&3)]
#pragma unroll
        for (int it = 0; it < 4; it++) {
            int u = t + 256 * it;
            int row = u >> 4, cb = u & 15;
            *(uint4*)&ph_lds[(cb >> 2) * 2048 + row * 32 + (((cb & 3) ^ ((row >> 1) & 3)) * 8)] =
                *(const uint4*)&phB[(size_t)(c0 + row) * kCI + cb * 8];
        }
        // stage g chunk [128 ci][64 m] -> [ks2][ci][kblk^((ci>>1)&3)]
#pragma unroll
        for (int it = 0; it < 4; it++) {
            int u = t + 256 * it;
            int ci = u >> 3, mb = u & 7;
            *(uint4*)&g_lds[(mb >> 2) * 4096 + ci * 32 + (((mb & 3) ^ ((ci >> 1) & 3)) * 8)] =
                *(const uint4*)&gB[(size_t)ci * kM + c0 + mb * 8];
        }
        __syncthreads();

        // S' = phi(64m x 128k) . theta^T : 4 mt-tiles, C-col = n
        f32x4 sacc[4];
#pragma unroll
        for (int mt = 0; mt < 4; mt++) sacc[mt] = (f32x4){0.f, 0.f, 0.f, 0.f};
#pragma unroll
        for (int ks = 0; ks < 4; ks++)
#pragma unroll
            for (int mt = 0; mt < 4; mt++) {
                bf16x8 a = *(const bf16x8*)&ph_lds[ks * 2048 + (mt * 16 + l15) * 32 +
                                                   ((quad ^ sw) * 8)];
                sacc[mt] = __builtin_amdgcn_mfma_f32_16x16x32_bf16(a, thf[ks], sacc[mt], 0, 0, 0);
            }

        // online softmax over m (per-lane n = l15; reduce across quads)
        float mc = -1e30f;
#pragma unroll
        for (int mt = 0; mt < 4; mt++)
#pragma unroll
            for (int r = 0; r < 4; r++) mc = fmaxf(mc, sacc[mt][r]);
        mc = fmaxf(mc, __shfl_xor(mc, 16, 64));
        mc = fmaxf(mc, __shfl_xor(mc, 32, 64));
        float mn = fmaxf(m_, mc);
        int resc = __any(mn != m_);
        float alpha = __expf(m_ - mn);
        m_ = mn;
        float rs = 0.f;
#pragma unroll
        for (int mt = 0; mt < 4; mt++)
#pragma unroll
            for (int r = 0; r < 4; r++) {
                float p = __expf(sacc[mt][r] - mn);
                sacc[mt][r] = p;
                rs += p;
            }
        rs += __shfl_xor(rs, 16, 64);
        rs += __shfl_xor(rs, 32, 64);
        l_ = l_ * alpha + rs;
        if (resc) {
#pragma unroll
            for (int ct = 0; ct < 8; ct++)
#pragma unroll
                for (int r = 0; r < 4; r++) oacc[ct][r] *= alpha;
        }
        // scatter P' -> per-wave frag LDS [frag][col=l15][k] swizzled; b32, ~2-way
#pragma unroll
        for (int mt = 0; mt < 4; mt++)
#pragma unroll
            for (int h = 0; h < 2; h++) {
                u32 d = (u32)f2bf(sacc[mt][2 * h]) | ((u32)f2bf(sacc[mt][2 * h + 1]) << 16);
                int m = mt * 16 + quad * 4 + 2 * h;
                int frag = m >> 5;
                int kblk = ((m >> 3) & 3);
                int j = (quad & 1) * 4 + 2 * h;
                *(u32*)&pw[frag * 512 + l15 * 32 + ((kblk ^ sw) * 8) + j] = d;
            }

        // O' += G^T(128ci x 64m) . P'(64m x n)   (per-wave p buffer, no barrier)
#pragma unroll
        for (int ks2 = 0; ks2 < 2; ks2++) {
            bf16x8 bfrag = *(const bf16x8*)&pw[ks2 * 512 + l15 * 32 + ((quad ^ sw) * 8)];
#pragma unroll
            for (int ct = 0; ct < 8; ct++) {
                bf16x8 a = *(const bf16x8*)&g_lds[ks2 * 4096 + (ct * 16 + l15) * 32 +
                                                  ((quad ^ sw) * 8)];
                oacc[ct] = __builtin_amdgcn_mfma_f32_16x16x32_bf16(a, bfrag, oacc[ct], 0, 0, 0);
            }
        }
    }

    // epilogue: y[n][ci] = O'/l ; n = col = l15
    float inv = 1.0f / l_;
    int n = n0 + w * 16 + l15;
    u16* yr = y + ((size_t)(b * kN) + n) * kCI + quad * 4;
#pragma unroll
    for (int ct = 0; ct < 8; ct++) {
        uint2 pk;
        pk.x = (u32)f2bf(oacc[ct][0] * inv) | ((u32)f2bf(oacc[ct][1] * inv) << 16);
        pk.y = (u32)f2bf(oacc[ct][2] * inv) | ((u32)f2bf(oacc[ct][3] * inv) << 16);
        *(uint2*)&yr[ct * 16] = pk;
    }
}

// ---------------------------------------------------------------------------
// MFMA final conv: out[b][co][n] = Wws(bf16 [256][128]) . y(bf16 [b][n][128])
//                  + bb[co] + v[b][co][n]   (fp32 out)
// ---------------------------------------------------------------------------
__global__ __launch_bounds__(256) void final_kernel(const u16* __restrict__ y,
                                                    const u16* __restrict__ Wws,
                                                    const float* __restrict__ bb,
                                                    const float* __restrict__ v,
                                                    float* __restrict__ out) {
    __shared__ __align__(16) u16 y_lds[64 * 136];
    int t = threadIdx.x, b = blockIdx.y, n0 = blockIdx.x * 64;
    int w = t >> 6, lane = t & 63, l15 = lane & 15, quad = lane >> 4;

#pragma unroll
    for (int i = 0; i < 4; i++) {
        int u = t + 256 * i;
        int row = u >> 4, blk = u & 15;
        *(uint4*)&y_lds[row * 136 + blk * 8] =
            *(const uint4*)&y[(size_t)(b * kN + n0 + row) * kCI + blk * 8];
    }
    __syncthreads();

    bf16x8 af[4];
#pragma unroll
    for (int ks = 0; ks < 4; ks++)
        af[ks] = *(const bf16x8*)&y_lds[(w * 16 + l15) * 136 + ks * 32 + quad * 8];

#pragma unroll
    for (int ct = 0; ct < 16; ct++) {
        f32x4 a = (f32x4){0.f, 0.f, 0.f, 0.f};
#pragma unroll
        for (int ks = 0; ks < 4; ks++) {
            bf16x8 bf = *(const bf16x8*)&Wws[(ct * 16 + l15) * kCI + ks * 32 + quad * 8];
            a = __builtin_amdgcn_mfma_f32_16x16x32_bf16(af[ks], bf, a, 0, 0, 0);
        }
        int co = ct * 16 + l15;
        float bbv = bb[co];
        size_t base = (size_t)(b * kC + co) * kN + n0 + w * 16 + quad * 4;
        float4 vv = *(const float4*)&v[base];
        float4 ov;
        ov.x = a[0] + bbv + vv.x;
        ov.y = a[1] + bbv + vv.y;
        ov.z = a[2] + bbv + vv.z;
        ov.w = a[3] + bbv + vv.w;
        *(float4*)&out[base] = ov;
    }
}

// ---------------------------------------------------------------------------
extern "C" void kernel_launch(void* const* d_in, const int* in_sizes, int n_in,
                              void* d_out, int out_size, void* d_ws, size_t ws_size,
                              hipStream_t stream) {
    (void)in_sizes; (void)n_in; (void)out_size; (void)ws_size;
    const float* q     = (const float*)d_in[0];
    const float* k     = (const float*)d_in[1];
    const float* v     = (const float*)d_in[2];
    const float* Wg    = (const float*)d_in[3];
    const float* bg    = (const float*)d_in[4];
    const float* Wth   = (const float*)d_in[5];
    const float* bth   = (const float*)d_in[6];
    const float* Wph   = (const float*)d_in[7];
    const float* bph   = (const float*)d_in[8];
    const float* Ww    = (const float*)d_in[9];
    const float* bw    = (const float*)d_in[10];
    const float* gamma = (const float*)d_in[11];
    const float* beta  = (const float*)d_in[12];
    const float* mean  = (const float*)d_in[13];
    const float* var   = (const float*)d_in[14];
    float* out = (float*)d_out;

    u16* wsu = (u16*)d_ws;
    u16*   theta = wsu;                       // 4M u16
    u16*   phi   = theta + 4194304;           // 1M u16
    u16*   gbuf  = phi + 1048576;             // 1M u16
    u16*   ybuf  = gbuf + 1048576;            // 4M u16
    u16*   Wthb  = ybuf + 4194304;
    u16*   Wphb  = Wthb + 32768;
    u16*   Wgb   = Wphb + 32768;
    u16*   Wwsb  = Wgb + 32768;
    float* bbuf  = (float*)(Wwsb + 32768);

    prep_kernel<<<dim3(512), 256, 0, stream>>>(Wth, Wph, Wg, Ww, bw, gamma, beta,
                                               mean, var, Wthb, Wphb, Wgb, Wwsb, bbuf);
    convth_kernel<<<dim3(64, 8), 256, 0, stream>>>(k, Wthb, bth, theta);
    convpg_kernel<<<dim3(16, 8, 2), 256, 0, stream>>>(q, v, Wphb, Wgb, bph, bg, phi, gbuf);
    attn_kernel<<<dim3(64, 8), 256, 0, stream>>>(theta, phi, gbuf, ybuf);
    final_kernel<<<dim3(64, 8), 256, 0, stream>>>(ybuf, Wwsb, bbuf, v, out);
}